// Round 1
// baseline (109.964 us; speedup 1.0000x reference)
//
#include <hip/hip_runtime.h>
#include <math.h>

#define N_OCT 16
#define NS    32768
#define TPB   512
#define SPT   (NS / TPB)   // 64 samples per thread
#define N_BE  512          // B*E = 8*64

// One block per (b,e) row. Thread t owns samples s = k*TPB + t.
// Phase kept in REVOLUTIONS so v_sin_f32/v_cos_f32 builtins apply directly.
// Main loop: per-octave 2x2 rotation recurrence (5 fma-class ops), no transcendentals.
__global__ __launch_bounds__(TPB, 1)
void f0res_kernel(const float* __restrict__ f0_in,
                  const float* __restrict__ dc_in,
                  const float* __restrict__ fs_in,
                  float* __restrict__ out)
{
    extern __shared__ float smem[];          // NS floats = 128 KiB dynamic LDS
    __shared__ float wmax[TPB / 64];

    const int be = blockIdx.x;
    const int t  = threadIdx.x;

    const float f0a = fabsf(f0_in[be]);
    const float dc  = dc_in[be];
    const float fs  = fs_in[be];

    const float MINF = (float)(20.0 / 11025.0);
    const float FRNG = (float)(3000.0 / 11025.0 - 20.0 / 11025.0);

    // double sigmoid (reference applies sigmoid twice), decay ladder
    const float s1    = 1.0f / (1.0f + __expf(-dc));
    const float dv    = 1.0f / (1.0f + __expf(-s1));
    const float decay = 0.01f + dv * 0.9801f;          // (1-0.01)*0.99
    const float logd  = __logf(decay + 1e-12f);
    const float f0r   = (MINF + f0a * FRNG) * 3.14159274101257324f;

    float sv[N_OCT], cv[N_OCT], cd[N_OCT], sd[N_OCT], amp[N_OCT];
    float cl = 0.f, cf = 0.f;
    const double inv2pi = 0.15915494309189535;
    #pragma unroll
    for (int o = 0; o < N_OCT; ++o) {
        cl += logd;                                    // float32 cumsum like ref
        cf += fs;
        float ed  = __expf(cl);                        // decay^(o+1)
        float f0s = f0r * cf;                          // rad/sample, float32
        float a   = ed;
        if (!(f0s < 1.0f)) { a = 0.0f; f0s = 0.0f; }   // nyquist cutoff
        amp[o] = a;
        double r  = (double)f0s * inv2pi;              // revolutions/sample (exact-ish)
        double p0 = r * (double)(t + 1);               // phase at first owned sample
        p0 -= floor(p0);
        sv[o] = __builtin_amdgcn_sinf((float)p0);
        cv[o] = __builtin_amdgcn_cosf((float)p0);
        double st = r * (double)TPB;                   // step = TPB samples
        st -= floor(st);
        sd[o] = __builtin_amdgcn_sinf((float)st);
        cd[o] = __builtin_amdgcn_cosf((float)st);
    }

    float lmax = 0.0f;
    #pragma unroll 4
    for (int k = 0; k < SPT; ++k) {
        float acc = 0.0f;
        #pragma unroll
        for (int o = 0; o < N_OCT; ++o) {
            acc = fmaf(amp[o], sv[o], acc);
            float ns = fmaf(sv[o], cd[o],  cv[o] * sd[o]);
            float nc = fmaf(cv[o], cd[o], -(sv[o] * sd[o]));
            sv[o] = ns;
            cv[o] = nc;
        }
        smem[k * TPB + t] = acc;                       // coalesced, conflict-free
        lmax = fmaxf(lmax, fabsf(acc));
    }

    // block max reduction: wave shuffle then tiny LDS
    #pragma unroll
    for (int off = 32; off > 0; off >>= 1)
        lmax = fmaxf(lmax, __shfl_down(lmax, off, 64));
    if ((t & 63) == 0) wmax[t >> 6] = lmax;
    __syncthreads();
    float bmax = wmax[0];
    #pragma unroll
    for (int w = 1; w < TPB / 64; ++w) bmax = fmaxf(bmax, wmax[w]);

    const float norm = 1.0f / (bmax + 1e-8f);
    float4*       out4 = (float4*)(out + (size_t)be * NS);
    const float4* s4   = (const float4*)smem;
    #pragma unroll
    for (int j = 0; j < NS / 4 / TPB; ++j) {           // 16 float4 stores/thread
        int i = j * TPB + t;
        float4 v = s4[i];
        v.x *= norm; v.y *= norm; v.z *= norm; v.w *= norm;
        out4[i] = v;
    }
}

extern "C" void kernel_launch(void* const* d_in, const int* in_sizes, int n_in,
                              void* d_out, int out_size, void* d_ws, size_t ws_size,
                              hipStream_t stream) {
    const float* f0 = (const float*)d_in[0];
    const float* dc = (const float*)d_in[1];
    const float* fs = (const float*)d_in[3];   // d_in[2] is "unused"
    float* out = (float*)d_out;
    hipLaunchKernelGGL(f0res_kernel, dim3(N_BE), dim3(TPB),
                       NS * sizeof(float), stream, f0, dc, fs, out);
}